// Round 13
// baseline (370.617 us; speedup 1.0000x reference)
//
#include <hip/hip_runtime.h>

typedef unsigned int uint;
typedef unsigned short ushort;

#define NN 50000
#define NE 600000
#define DIM 128
#define KD 384   // K*DIM
#define PADK 40  // LDS row stride (ushorts) for MFMA tiles

typedef __attribute__((ext_vector_type(8))) short short8;
typedef __attribute__((ext_vector_type(4))) float float4v;

static __device__ __forceinline__ ushort f2b(float f) {   // fp32 -> bf16 RNE
    uint u = __float_as_uint(f);
    return (ushort)((u + 0x7FFFu + ((u >> 16) & 1u)) >> 16);
}
static __device__ __forceinline__ float blo(uint u) { return __uint_as_float(u << 16); }
static __device__ __forceinline__ float bhi(uint u) { return __uint_as_float(u & 0xFFFF0000u); }

// blocks 0..48: zero cnt (50176 ints); blocks 49..624: transpose weights
// cheb_w [3][K=384][N=128] fp32 -> Wt [3][N=128][K=384] bf16
__global__ void k_init(int* __restrict__ cnt, const float* __restrict__ cw,
                       ushort* __restrict__ wt) {
    if (blockIdx.x < 49) {
        int i = blockIdx.x * 256 + threadIdx.x;
        if (i < 12544) ((int4*)cnt)[i] = make_int4(0, 0, 0, 0);
    } else {
        int i = (blockIdx.x - 49) * 256 + threadIdx.x;
        if (i < 3 * KD * DIM) {
            int l = i / (KD * DIM), rem = i - l * (KD * DIM);
            int k = rem >> 7, n = rem & 127;
            wt[(size_t)l * KD * DIM + (size_t)n * KD + k] = f2b(cw[i]);
        }
    }
}

__global__ void k_hist(const int* __restrict__ dst, int* __restrict__ cnt) {
    int e = blockIdx.x * 256 + threadIdx.x;
    if (e < NE) atomicAdd(&cnt[dst[e]], 1);
}

// Block scan of cnt -> incl, block totals -> bsums; also emits dinv.
__global__ __launch_bounds__(256) void k_scan1(const int* __restrict__ cnt,
                                               int* __restrict__ incl,
                                               int* __restrict__ bsums,
                                               float* __restrict__ dinv) {
    __shared__ int sh[256];
    int i = blockIdx.x * 256 + threadIdx.x;
    int v = (i < NN) ? cnt[i] : 0;
    if (i < NN) dinv[i] = rsqrtf((float)(v + 1));   // +1 self-loop
    sh[threadIdx.x] = v;
    __syncthreads();
    for (int d = 1; d < 256; d <<= 1) {
        int t = (threadIdx.x >= d) ? sh[threadIdx.x - d] : 0;
        __syncthreads();
        sh[threadIdx.x] += t;
        __syncthreads();
    }
    incl[i] = sh[threadIdx.x];
    if (threadIdx.x == 255) bsums[blockIdx.x] = sh[255];
}

// Fused: each block prefix-sums the 196 block totals itself, then emits offs.
__global__ __launch_bounds__(256) void k_scan3(const int* __restrict__ cnt,
                                               int* __restrict__ incl_cursor,
                                               const int* __restrict__ bsums,
                                               int* __restrict__ offs) {
    __shared__ int sh[256];
    __shared__ int boff;
    int tid = threadIdx.x;
    int v = (tid < 196) ? bsums[tid] : 0;
    sh[tid] = v;
    __syncthreads();
    for (int d = 1; d < 256; d <<= 1) {
        int t = (tid >= d) ? sh[tid - d] : 0;
        __syncthreads();
        sh[tid] += t;
        __syncthreads();
    }
    if (tid == blockIdx.x) boff = sh[tid] - v;   // exclusive prefix for this block
    __syncthreads();
    int i = blockIdx.x * 256 + tid;
    if (i >= NN) return;
    int excl = incl_cursor[i] - cnt[i] + boff;
    offs[i] = excl;
    incl_cursor[i] = excl;   // becomes the fill cursor
    if (i == NN - 1) offs[NN] = NE;
}

__global__ void k_fill(const int* __restrict__ src, const int* __restrict__ dst,
                       int* __restrict__ cursor, ushort* __restrict__ csr_src) {
    int e = blockIdx.x * 256 + threadIdx.x;
    if (e < NE) {
        int p = atomicAdd(&cursor[dst[e]], 1);
        csr_src[p] = (ushort)src[e];   // src < 50000 fits 16 bits
    }
}

// Layer-1 gather1 via rank-1 X0 = w*lin_w + lin_b (scalar reductions only).
// Also writes Pb = bf16(X0) (k_feat fused).
__global__ __launch_bounds__(256) void k_gather1_l1(
        const float* __restrict__ w, const float* __restrict__ lw,
        const float* __restrict__ lb, const int* __restrict__ offs,
        const ushort* __restrict__ csr_src, const float* __restrict__ dinv,
        ushort* __restrict__ Qb, ushort* __restrict__ Pb) {
    int n = blockIdx.x * 4 + (threadIdx.x >> 6);
    int lane = threadIdx.x & 63;
    int j0 = offs[n], j1 = offs[n + 1];
    float dn = dinv[n];
    float sA = 0.f, sB = 0.f;
    for (int j = j0 + lane; j < j1; j += 64) {
        int s = csr_src[j];
        float ds = dinv[s];
        sA = fmaf(ds, w[s], sA);
        sB += ds;
    }
#pragma unroll
    for (int off = 32; off > 0; off >>= 1) {
        sA += __shfl_down(sA, off, 64);
        sB += __shfl_down(sB, off, 64);
    }
    sA = __shfl(sA, 0, 64) * dn;
    sB = __shfl(sB, 0, 64) * dn;
    float id = dn * dn;
    float wn = w[n];
    float lw0 = lw[2 * lane], lw1 = lw[2 * lane + 1];
    float lb0 = lb[2 * lane], lb1 = lb[2 * lane + 1];
    float x0a = wn * lw0 + lb0, x0b = wn * lw1 + lb1;
    ushort2 pb2; pb2.x = f2b(x0a); pb2.y = f2b(x0b);
    ((ushort2*)(Pb + (size_t)n * DIM))[lane] = pb2;
    ushort2 ub;
    ub.x = f2b(-(sA * lw0 + sB * lb0 + x0a * id));
    ub.y = f2b(-(sA * lw1 + sB * lb1 + x0b * id));
    ((ushort2*)(Qb + (size_t)n * DIM))[lane] = ub;
}

#define ACC8(u_, w_)                                        \
    a[0] = fmaf(w_, blo((u_).x), a[0]);                     \
    a[1] = fmaf(w_, bhi((u_).x), a[1]);                     \
    a[2] = fmaf(w_, blo((u_).y), a[2]);                     \
    a[3] = fmaf(w_, bhi((u_).y), a[3]);                     \
    a[4] = fmaf(w_, blo((u_).z), a[4]);                     \
    a[5] = fmaf(w_, bhi((u_).z), a[5]);                     \
    a[6] = fmaf(w_, blo((u_).w), a[6]);                     \
    a[7] = fmaf(w_, bhi((u_).w), a[7]);

// Quarter-wave gather: 4 nodes per 64-wave (16-lane groups), lane owns 8 dims
// as one uint4 (16B x 16 lanes = 256B/row, coalesced). 4x independent load
// streams per wave vs full-wave. Qb[n] = bf16( -( sum w_e*Xb[src] + Xb[n]/deg ) )
__global__ __launch_bounds__(256) void k_gather1(
        const ushort* __restrict__ Xb, const int* __restrict__ offs,
        const ushort* __restrict__ csr_src, const float* __restrict__ dinv,
        ushort* __restrict__ Qb) {
    int n = blockIdx.x * 16 + (threadIdx.x >> 4);
    int lane = threadIdx.x & 15;
    int j0 = offs[n], j1 = offs[n + 1];
    float dn = dinv[n];
    float a[8];
#pragma unroll
    for (int q = 0; q < 8; ++q) a[q] = 0.f;
    const uint4* Xu = (const uint4*)Xb;   // row = 16 uint4
    for (int base = j0; base < j1; base += 16) {
        int m = j1 - base; if (m > 16) m = 16;
        int s = 0; float wv = 0.f;
        if (lane < m) { s = csr_src[base + lane]; wv = dinv[s] * dn; }
        int t = 0;
        for (; t + 8 <= m; t += 8) {
            uint4 u[8]; float wb[8];
#pragma unroll
            for (int q = 0; q < 8; ++q) {
                int sq = __shfl(s, t + q, 16);
                wb[q] = __shfl(wv, t + q, 16);
                u[q] = Xu[(size_t)sq * 16 + lane];
            }
#pragma unroll
            for (int q = 0; q < 8; ++q) { ACC8(u[q], wb[q]); }
        }
        for (; t + 4 <= m; t += 4) {
            uint4 u[4]; float wb[4];
#pragma unroll
            for (int q = 0; q < 4; ++q) {
                int sq = __shfl(s, t + q, 16);
                wb[q] = __shfl(wv, t + q, 16);
                u[q] = Xu[(size_t)sq * 16 + lane];
            }
#pragma unroll
            for (int q = 0; q < 4; ++q) { ACC8(u[q], wb[q]); }
        }
        for (; t < m; ++t) {
            int ss = __shfl(s, t, 16);
            float ww = __shfl(wv, t, 16);
            uint4 u = Xu[(size_t)ss * 16 + lane];
            ACC8(u, ww);
        }
    }
    float id = dn * dn;
    uint4 un = Xu[(size_t)n * 16 + lane];
    uint4 ow;
    ow.x = (uint)f2b(-(a[0] + blo(un.x) * id)) | ((uint)f2b(-(a[1] + bhi(un.x) * id)) << 16);
    ow.y = (uint)f2b(-(a[2] + blo(un.y) * id)) | ((uint)f2b(-(a[3] + bhi(un.y) * id)) << 16);
    ow.z = (uint)f2b(-(a[4] + blo(un.z) * id)) | ((uint)f2b(-(a[5] + bhi(un.z) * id)) << 16);
    ow.w = (uint)f2b(-(a[6] + blo(un.w) * id)) | ((uint)f2b(-(a[7] + bhi(un.w) * id)) << 16);
    ((uint4*)(Qb + (size_t)n * DIM))[lane] = ow;
}

// Rb[n] = bf16( -2*( sum w_e*X1b[src] + X1b[n]/deg ) - X0b[n] )
__global__ __launch_bounds__(256) void k_gather2(
        const ushort* __restrict__ X1b, const ushort* __restrict__ X0b,
        const int* __restrict__ offs, const ushort* __restrict__ csr_src,
        const float* __restrict__ dinv, ushort* __restrict__ Rb) {
    int n = blockIdx.x * 16 + (threadIdx.x >> 4);
    int lane = threadIdx.x & 15;
    int j0 = offs[n], j1 = offs[n + 1];
    float dn = dinv[n];
    float a[8];
#pragma unroll
    for (int q = 0; q < 8; ++q) a[q] = 0.f;
    const uint4* Xu = (const uint4*)X1b;
    for (int base = j0; base < j1; base += 16) {
        int m = j1 - base; if (m > 16) m = 16;
        int s = 0; float wv = 0.f;
        if (lane < m) { s = csr_src[base + lane]; wv = dinv[s] * dn; }
        int t = 0;
        for (; t + 8 <= m; t += 8) {
            uint4 u[8]; float wb[8];
#pragma unroll
            for (int q = 0; q < 8; ++q) {
                int sq = __shfl(s, t + q, 16);
                wb[q] = __shfl(wv, t + q, 16);
                u[q] = Xu[(size_t)sq * 16 + lane];
            }
#pragma unroll
            for (int q = 0; q < 8; ++q) { ACC8(u[q], wb[q]); }
        }
        for (; t + 4 <= m; t += 4) {
            uint4 u[4]; float wb[4];
#pragma unroll
            for (int q = 0; q < 4; ++q) {
                int sq = __shfl(s, t + q, 16);
                wb[q] = __shfl(wv, t + q, 16);
                u[q] = Xu[(size_t)sq * 16 + lane];
            }
#pragma unroll
            for (int q = 0; q < 4; ++q) { ACC8(u[q], wb[q]); }
        }
        for (; t < m; ++t) {
            int ss = __shfl(s, t, 16);
            float ww = __shfl(wv, t, 16);
            uint4 u = Xu[(size_t)ss * 16 + lane];
            ACC8(u, ww);
        }
    }
    float id = dn * dn;
    uint4 u1n = Xu[(size_t)n * 16 + lane];
    uint4 u0n = ((const uint4*)X0b)[(size_t)n * 16 + lane];
    uint4 ow;
    ow.x = (uint)f2b(-2.f * (a[0] + blo(u1n.x) * id) - blo(u0n.x))
         | ((uint)f2b(-2.f * (a[1] + bhi(u1n.x) * id) - bhi(u0n.x)) << 16);
    ow.y = (uint)f2b(-2.f * (a[2] + blo(u1n.y) * id) - blo(u0n.y))
         | ((uint)f2b(-2.f * (a[3] + bhi(u1n.y) * id) - bhi(u0n.y)) << 16);
    ow.z = (uint)f2b(-2.f * (a[4] + blo(u1n.z) * id) - blo(u0n.z))
         | ((uint)f2b(-2.f * (a[5] + bhi(u1n.z) * id) - bhi(u0n.z)) << 16);
    ow.w = (uint)f2b(-2.f * (a[6] + blo(u1n.w) * id) - blo(u0n.w))
         | ((uint)f2b(-2.f * (a[7] + bhi(u1n.w) * id) - bhi(u0n.w)) << 16);
    ((uint4*)(Rb + (size_t)n * DIM))[lane] = ow;
}

// MFMA GEMM: outb = bf16(relu([X0|X1|X2] @ W + bias)). 128x128 per block,
// 4 waves each 64x64 quadrant as 4x4 16x16x32 bf16 MFMA tiles.
// Aliasing (outb == X0b) safe: block reads only its own 128 rows, writes last.
__global__ __launch_bounds__(256) void k_gemm(
        const ushort* __restrict__ X0b, const ushort* __restrict__ X1b,
        const ushort* __restrict__ X2b, const ushort* __restrict__ Wt,
        const float* __restrict__ bias, ushort* __restrict__ outb) {
    __shared__ ushort As[128 * PADK];
    __shared__ ushort Bs[128 * PADK];
    int tid = threadIdx.x;
    int nbase = blockIdx.x * 128;
    int wave = tid >> 6, lane = tid & 63;
    int wr = wave >> 1, wc = wave & 1;
    int l15 = lane & 15, quad = lane >> 4;

    float4v acc[4][4];
#pragma unroll
    for (int i = 0; i < 4; ++i)
#pragma unroll
        for (int j = 0; j < 4; ++j) acc[i][j] = (float4v)0.f;

    int srow = tid >> 1, shalf = tid & 1;
    int gm = nbase + srow; if (gm >= NN) gm = NN - 1;

    for (int c = 0; c < 12; ++c) {
        int part = c >> 2;
        int k0 = (c & 3) * 32;
        const ushort* Xp = (part == 0) ? X0b : ((part == 1) ? X1b : X2b);
        const uint4* ga = (const uint4*)(Xp + (size_t)gm * DIM + k0 + shalf * 16);
        uint4 a0 = ga[0], a1 = ga[1];
        const uint4* gb = (const uint4*)(Wt + (size_t)srow * KD + c * 32 + shalf * 16);
        uint4 b0 = gb[0], b1 = gb[1];
        __syncthreads();
        uint4* pa = (uint4*)(As + srow * PADK + shalf * 16);
        pa[0] = a0; pa[1] = a1;
        uint4* pb = (uint4*)(Bs + srow * PADK + shalf * 16);
        pb[0] = b0; pb[1] = b1;
        __syncthreads();
        short8 af[4], bf[4];
#pragma unroll
        for (int i = 0; i < 4; ++i) {
            af[i] = *(const short8*)(As + (wr * 64 + i * 16 + l15) * PADK + quad * 8);
            bf[i] = *(const short8*)(Bs + (wc * 64 + i * 16 + l15) * PADK + quad * 8);
        }
#pragma unroll
        for (int i = 0; i < 4; ++i)
#pragma unroll
            for (int j = 0; j < 4; ++j)
                acc[i][j] = __builtin_amdgcn_mfma_f32_16x16x32_bf16(
                    af[i], bf[j], acc[i][j], 0, 0, 0);
    }

    float bv[4];
#pragma unroll
    for (int j = 0; j < 4; ++j) bv[j] = bias[wc * 64 + j * 16 + l15];
#pragma unroll
    for (int i = 0; i < 4; ++i) {
#pragma unroll
        for (int r = 0; r < 4; ++r) {
            int node = nbase + wr * 64 + i * 16 + quad * 4 + r;
            if (node < NN) {
#pragma unroll
                for (int j = 0; j < 4; ++j) {
                    int col = wc * 64 + j * 16 + l15;
                    outb[(size_t)node * DIM + col] =
                        f2b(fmaxf(acc[i][j][r] + bv[j], 0.f));
                }
            }
        }
    }
}

// Last-layer GEMM with fused prediction head.
__global__ __launch_bounds__(256) void k_gemm_pred(
        const ushort* __restrict__ X0b, const ushort* __restrict__ X1b,
        const ushort* __restrict__ X2b, const ushort* __restrict__ Wt,
        const float* __restrict__ bias, const float* __restrict__ pw,
        const float* __restrict__ pb, float* __restrict__ logits) {
    __shared__ ushort As[128 * PADK];
    __shared__ ushort Bs[128 * PADK];
    __shared__ float lsum[128];
    int tid = threadIdx.x;
    int nbase = blockIdx.x * 128;
    int wave = tid >> 6, lane = tid & 63;
    int wr = wave >> 1, wc = wave & 1;
    int l15 = lane & 15, quad = lane >> 4;

    float4v acc[4][4];
#pragma unroll
    for (int i = 0; i < 4; ++i)
#pragma unroll
        for (int j = 0; j < 4; ++j) acc[i][j] = (float4v)0.f;

    int srow = tid >> 1, shalf = tid & 1;
    int gm = nbase + srow; if (gm >= NN) gm = NN - 1;

    for (int c = 0; c < 12; ++c) {
        int part = c >> 2;
        int k0 = (c & 3) * 32;
        const ushort* Xp = (part == 0) ? X0b : ((part == 1) ? X1b : X2b);
        const uint4* ga = (const uint4*)(Xp + (size_t)gm * DIM + k0 + shalf * 16);
        uint4 a0 = ga[0], a1 = ga[1];
        const uint4* gb = (const uint4*)(Wt + (size_t)srow * KD + c * 32 + shalf * 16);
        uint4 b0 = gb[0], b1 = gb[1];
        __syncthreads();
        uint4* pa = (uint4*)(As + srow * PADK + shalf * 16);
        pa[0] = a0; pa[1] = a1;
        uint4* pb2 = (uint4*)(Bs + srow * PADK + shalf * 16);
        pb2[0] = b0; pb2[1] = b1;
        __syncthreads();
        short8 af[4], bf[4];
#pragma unroll
        for (int i = 0; i < 4; ++i) {
            af[i] = *(const short8*)(As + (wr * 64 + i * 16 + l15) * PADK + quad * 8);
            bf[i] = *(const short8*)(Bs + (wc * 64 + i * 16 + l15) * PADK + quad * 8);
        }
#pragma unroll
        for (int i = 0; i < 4; ++i)
#pragma unroll
            for (int j = 0; j < 4; ++j)
                acc[i][j] = __builtin_amdgcn_mfma_f32_16x16x32_bf16(
                    af[i], bf[j], acc[i][j], 0, 0, 0);
    }

    __syncthreads();
    if (tid < 128) lsum[tid] = 0.f;
    __syncthreads();
    float bv[4], pwv[4];
#pragma unroll
    for (int j = 0; j < 4; ++j) {
        int col = wc * 64 + j * 16 + l15;
        bv[j] = bias[col];
        pwv[j] = pw[col];
    }
#pragma unroll
    for (int i = 0; i < 4; ++i) {
#pragma unroll
        for (int r = 0; r < 4; ++r) {
            float local = 0.f;
#pragma unroll
            for (int j = 0; j < 4; ++j)
                local = fmaf(fmaxf(acc[i][j][r] + bv[j], 0.f), pwv[j], local);
            local += __shfl_xor(local, 1, 64);
            local += __shfl_xor(local, 2, 64);
            local += __shfl_xor(local, 4, 64);
            local += __shfl_xor(local, 8, 64);
            if (l15 == 0)
                atomicAdd(&lsum[wr * 64 + i * 16 + quad * 4 + r], local);
        }
    }
    __syncthreads();
    if (tid < 128) {
        int node = nbase + tid;
        if (node < NN) logits[node] = lsum[tid] + pb[0];
    }
}

extern "C" void kernel_launch(void* const* d_in, const int* in_sizes, int n_in,
                              void* d_out, int out_size, void* d_ws, size_t ws_size,
                              hipStream_t stream) {
    int i_weights = 0, i_src = 1, i_dst = 2, i_lw = 3, i_lb = 4,
        i_cw = 5, i_cb = 6, i_pw = 7, i_pb = 8;
    {
        int seen600k = 0, seen128 = 0;
        for (int i = 0; i < n_in; ++i) {
            int s = in_sizes[i];
            if (s == 50000) i_weights = i;
            else if (s == 600000) { if (seen600k == 0) i_src = i; else i_dst = i; ++seen600k; }
            else if (s == 128) { if (seen128 == 0) i_lw = i; else if (seen128 == 1) i_lb = i; else i_pw = i; ++seen128; }
            else if (s == 147456) i_cw = i;
            else if (s == 384) i_cb = i;
            else if (s == 1) i_pb = i;
        }
    }
    const float* weights = (const float*)d_in[i_weights];
    const int*   src     = (const int*)d_in[i_src];
    const int*   dst     = (const int*)d_in[i_dst];
    const float* lin_w   = (const float*)d_in[i_lw];
    const float* lin_b   = (const float*)d_in[i_lb];
    const float* cheb_w  = (const float*)d_in[i_cw];
    const float* cheb_b  = (const float*)d_in[i_cb];
    const float* pred_w  = (const float*)d_in[i_pw];
    const float* pred_b  = (const float*)d_in[i_pb];
    float* out = (float*)d_out;

    // Workspace (~44 MB):
    float*  ws      = (float*)d_ws;
    float*  dinv    = ws;                            // 50048 floats
    int*    offs    = (int*)(ws + 50048);            // 50056 ints
    ushort* csr_u16 = (ushort*)(offs + 50056);       // 600000 ushorts (300032 int-slots)
    int*    cnt     = (int*)csr_u16 + 300032;        // 50176 ints
    int*    incl    = cnt + 50176;                   // 50176 ints
    int*    bsums   = incl + 50176;                  // 256 ints
    ushort* Pb      = (ushort*)(bsums + 256);        // 6.4M bf16 (X0 / state)
    ushort* Qb      = Pb + (size_t)NN * DIM;         // 6.4M bf16 (X1)
    ushort* Rb      = Qb + (size_t)NN * DIM;         // 6.4M bf16 (X2)
    ushort* Wtb     = Rb + (size_t)NN * DIM;         // 442368 bf16

    // --- CSR build + weight transpose (once per launch) ---
    k_init<<<625, 256, 0, stream>>>(cnt, cheb_w, Wtb);
    k_hist<<<2344, 256, 0, stream>>>(dst, cnt);
    k_scan1<<<196, 256, 0, stream>>>(cnt, incl, bsums, dinv);
    k_scan3<<<196, 256, 0, stream>>>(cnt, incl, bsums, offs);
    k_fill<<<2344, 256, 0, stream>>>(src, dst, incl, csr_u16);

    // --- network ---
    // layer 1 (rank-1 gather1, writes Pb too)
    k_gather1_l1<<<12500, 256, 0, stream>>>(weights, lin_w, lin_b, offs, csr_u16,
                                            dinv, Qb, Pb);
    k_gather2<<<3125, 256, 0, stream>>>(Qb, Pb, offs, csr_u16, dinv, Rb);
    k_gemm<<<391, 256, 0, stream>>>(Pb, Qb, Rb, Wtb, cheb_b, Pb);
    // layer 2
    k_gather1<<<3125, 256, 0, stream>>>(Pb, offs, csr_u16, dinv, Qb);
    k_gather2<<<3125, 256, 0, stream>>>(Qb, Pb, offs, csr_u16, dinv, Rb);
    k_gemm<<<391, 256, 0, stream>>>(Pb, Qb, Rb, Wtb + (size_t)KD * DIM,
                                    cheb_b + DIM, Pb);
    // layer 3 (fused prediction head)
    k_gather1<<<3125, 256, 0, stream>>>(Pb, offs, csr_u16, dinv, Qb);
    k_gather2<<<3125, 256, 0, stream>>>(Qb, Pb, offs, csr_u16, dinv, Rb);
    k_gemm_pred<<<391, 256, 0, stream>>>(Pb, Qb, Rb, Wtb + (size_t)2 * KD * DIM,
                                         cheb_b + 2 * DIM, pred_w, pred_b, out);
}

// Round 14
// 360.737 us; speedup vs baseline: 1.0274x; 1.0274x over previous
//
#include <hip/hip_runtime.h>

typedef unsigned int uint;
typedef unsigned short ushort;

#define NN 50000
#define NE 600000
#define DIM 128
#define KD 384   // K*DIM
#define PADK 40  // LDS row stride (ushorts) for MFMA tiles

typedef __attribute__((ext_vector_type(8))) short short8;
typedef __attribute__((ext_vector_type(4))) float float4v;

static __device__ __forceinline__ ushort f2b(float f) {   // fp32 -> bf16 RNE
    uint u = __float_as_uint(f);
    return (ushort)((u + 0x7FFFu + ((u >> 16) & 1u)) >> 16);
}
static __device__ __forceinline__ float blo(uint u) { return __uint_as_float(u << 16); }
static __device__ __forceinline__ float bhi(uint u) { return __uint_as_float(u & 0xFFFF0000u); }

// blocks 0..48: zero cnt (50176 ints); blocks 49..624: transpose weights
// cheb_w [3][K=384][N=128] fp32 -> Wt [3][N=128][K=384] bf16
__global__ void k_init(int* __restrict__ cnt, const float* __restrict__ cw,
                       ushort* __restrict__ wt) {
    if (blockIdx.x < 49) {
        int i = blockIdx.x * 256 + threadIdx.x;
        if (i < 12544) ((int4*)cnt)[i] = make_int4(0, 0, 0, 0);
    } else {
        int i = (blockIdx.x - 49) * 256 + threadIdx.x;
        if (i < 3 * KD * DIM) {
            int l = i / (KD * DIM), rem = i - l * (KD * DIM);
            int k = rem >> 7, n = rem & 127;
            wt[(size_t)l * KD * DIM + (size_t)n * KD + k] = f2b(cw[i]);
        }
    }
}

__global__ void k_hist(const int* __restrict__ dst, int* __restrict__ cnt) {
    int e = blockIdx.x * 256 + threadIdx.x;
    if (e < NE) atomicAdd(&cnt[dst[e]], 1);
}

// Block scan of cnt -> incl, block totals -> bsums; also emits dinv.
__global__ __launch_bounds__(256) void k_scan1(const int* __restrict__ cnt,
                                               int* __restrict__ incl,
                                               int* __restrict__ bsums,
                                               float* __restrict__ dinv) {
    __shared__ int sh[256];
    int i = blockIdx.x * 256 + threadIdx.x;
    int v = (i < NN) ? cnt[i] : 0;
    if (i < NN) dinv[i] = rsqrtf((float)(v + 1));   // +1 self-loop
    sh[threadIdx.x] = v;
    __syncthreads();
    for (int d = 1; d < 256; d <<= 1) {
        int t = (threadIdx.x >= d) ? sh[threadIdx.x - d] : 0;
        __syncthreads();
        sh[threadIdx.x] += t;
        __syncthreads();
    }
    incl[i] = sh[threadIdx.x];
    if (threadIdx.x == 255) bsums[blockIdx.x] = sh[255];
}

// Fused: each block prefix-sums the 196 block totals itself, then emits offs.
__global__ __launch_bounds__(256) void k_scan3(const int* __restrict__ cnt,
                                               int* __restrict__ incl_cursor,
                                               const int* __restrict__ bsums,
                                               int* __restrict__ offs) {
    __shared__ int sh[256];
    __shared__ int boff;
    int tid = threadIdx.x;
    int v = (tid < 196) ? bsums[tid] : 0;
    sh[tid] = v;
    __syncthreads();
    for (int d = 1; d < 256; d <<= 1) {
        int t = (tid >= d) ? sh[tid - d] : 0;
        __syncthreads();
        sh[tid] += t;
        __syncthreads();
    }
    if (tid == blockIdx.x) boff = sh[tid] - v;   // exclusive prefix for this block
    __syncthreads();
    int i = blockIdx.x * 256 + tid;
    if (i >= NN) return;
    int excl = incl_cursor[i] - cnt[i] + boff;
    offs[i] = excl;
    incl_cursor[i] = excl;   // becomes the fill cursor
    if (i == NN - 1) offs[NN] = NE;
}

__global__ void k_fill(const int* __restrict__ src, const int* __restrict__ dst,
                       int* __restrict__ cursor, ushort* __restrict__ csr_src) {
    int e = blockIdx.x * 256 + threadIdx.x;
    if (e < NE) {
        int p = atomicAdd(&cursor[dst[e]], 1);
        csr_src[p] = (ushort)src[e];   // src < 50000 fits 16 bits
    }
}

// Layer-1 gather1 via rank-1 X0 = w*lin_w + lin_b (scalar reductions only).
// Also writes Pb = bf16(X0) (k_feat fused).
__global__ __launch_bounds__(256) void k_gather1_l1(
        const float* __restrict__ w, const float* __restrict__ lw,
        const float* __restrict__ lb, const int* __restrict__ offs,
        const ushort* __restrict__ csr_src, const float* __restrict__ dinv,
        ushort* __restrict__ Qb, ushort* __restrict__ Pb) {
    int n = blockIdx.x * 4 + (threadIdx.x >> 6);
    int lane = threadIdx.x & 63;
    int j0 = offs[n], j1 = offs[n + 1];
    float dn = dinv[n];
    float sA = 0.f, sB = 0.f;
    for (int j = j0 + lane; j < j1; j += 64) {
        int s = csr_src[j];
        float ds = dinv[s];
        sA = fmaf(ds, w[s], sA);
        sB += ds;
    }
#pragma unroll
    for (int off = 32; off > 0; off >>= 1) {
        sA += __shfl_down(sA, off, 64);
        sB += __shfl_down(sB, off, 64);
    }
    sA = __shfl(sA, 0, 64) * dn;
    sB = __shfl(sB, 0, 64) * dn;
    float id = dn * dn;
    float wn = w[n];
    float lw0 = lw[2 * lane], lw1 = lw[2 * lane + 1];
    float lb0 = lb[2 * lane], lb1 = lb[2 * lane + 1];
    float x0a = wn * lw0 + lb0, x0b = wn * lw1 + lb1;
    ushort2 pb2; pb2.x = f2b(x0a); pb2.y = f2b(x0b);
    ((ushort2*)(Pb + (size_t)n * DIM))[lane] = pb2;
    ushort2 ub;
    ub.x = f2b(-(sA * lw0 + sB * lb0 + x0a * id));
    ub.y = f2b(-(sA * lw1 + sB * lb1 + x0b * id));
    ((ushort2*)(Qb + (size_t)n * DIM))[lane] = ub;
}

// Half-wave gather: 2 nodes per 64-wave (independent 32-lane halves), lane owns
// 4 dims as uint2. Qb[n] = bf16( -( sum w_e*Xb[src] + Xb[n]/deg ) )
__global__ __launch_bounds__(256) void k_gather1(
        const ushort* __restrict__ Xb, const int* __restrict__ offs,
        const ushort* __restrict__ csr_src, const float* __restrict__ dinv,
        ushort* __restrict__ Qb) {
    int n = blockIdx.x * 8 + (threadIdx.x >> 5);
    int lane = threadIdx.x & 31;
    int j0 = offs[n], j1 = offs[n + 1];
    float dn = dinv[n];
    float a0 = 0.f, a1 = 0.f, a2 = 0.f, a3 = 0.f;
    const uint2* Xu = (const uint2*)Xb;   // row = 32 uint2
    for (int base = j0; base < j1; base += 32) {
        int m = j1 - base; if (m > 32) m = 32;
        int s = 0; float wv = 0.f;
        if (lane < m) { s = csr_src[base + lane]; wv = dinv[s] * dn; }
        int t = 0;
        for (; t + 8 <= m; t += 8) {
            uint2 u[8]; float wb[8];
#pragma unroll
            for (int q = 0; q < 8; ++q) {
                int sq = __shfl(s, t + q, 32);
                wb[q] = __shfl(wv, t + q, 32);
                u[q] = Xu[(size_t)sq * 32 + lane];
            }
#pragma unroll
            for (int q = 0; q < 8; ++q) {
                a0 = fmaf(wb[q], blo(u[q].x), a0);
                a1 = fmaf(wb[q], bhi(u[q].x), a1);
                a2 = fmaf(wb[q], blo(u[q].y), a2);
                a3 = fmaf(wb[q], bhi(u[q].y), a3);
            }
        }
        for (; t + 4 <= m; t += 4) {
            uint2 u[4]; float wb[4];
#pragma unroll
            for (int q = 0; q < 4; ++q) {
                int sq = __shfl(s, t + q, 32);
                wb[q] = __shfl(wv, t + q, 32);
                u[q] = Xu[(size_t)sq * 32 + lane];
            }
#pragma unroll
            for (int q = 0; q < 4; ++q) {
                a0 = fmaf(wb[q], blo(u[q].x), a0);
                a1 = fmaf(wb[q], bhi(u[q].x), a1);
                a2 = fmaf(wb[q], blo(u[q].y), a2);
                a3 = fmaf(wb[q], bhi(u[q].y), a3);
            }
        }
        for (; t < m; ++t) {
            int ss = __shfl(s, t, 32);
            float ww = __shfl(wv, t, 32);
            uint2 u = Xu[(size_t)ss * 32 + lane];
            a0 = fmaf(ww, blo(u.x), a0); a1 = fmaf(ww, bhi(u.x), a1);
            a2 = fmaf(ww, blo(u.y), a2); a3 = fmaf(ww, bhi(u.y), a3);
        }
    }
    float id = dn * dn;
    uint2 un = Xu[(size_t)n * 32 + lane];
    uint2 ow;
    ow.x = (uint)f2b(-(a0 + blo(un.x) * id)) | ((uint)f2b(-(a1 + bhi(un.x) * id)) << 16);
    ow.y = (uint)f2b(-(a2 + blo(un.y) * id)) | ((uint)f2b(-(a3 + bhi(un.y) * id)) << 16);
    ((uint2*)(Qb + (size_t)n * DIM))[lane] = ow;
}

// Rb[n] = bf16( -2*( sum w_e*X1b[src] + X1b[n]/deg ) - X0b[n] )
__global__ __launch_bounds__(256) void k_gather2(
        const ushort* __restrict__ X1b, const ushort* __restrict__ X0b,
        const int* __restrict__ offs, const ushort* __restrict__ csr_src,
        const float* __restrict__ dinv, ushort* __restrict__ Rb) {
    int n = blockIdx.x * 8 + (threadIdx.x >> 5);
    int lane = threadIdx.x & 31;
    int j0 = offs[n], j1 = offs[n + 1];
    float dn = dinv[n];
    float a0 = 0.f, a1 = 0.f, a2 = 0.f, a3 = 0.f;
    const uint2* Xu = (const uint2*)X1b;
    for (int base = j0; base < j1; base += 32) {
        int m = j1 - base; if (m > 32) m = 32;
        int s = 0; float wv = 0.f;
        if (lane < m) { s = csr_src[base + lane]; wv = dinv[s] * dn; }
        int t = 0;
        for (; t + 8 <= m; t += 8) {
            uint2 u[8]; float wb[8];
#pragma unroll
            for (int q = 0; q < 8; ++q) {
                int sq = __shfl(s, t + q, 32);
                wb[q] = __shfl(wv, t + q, 32);
                u[q] = Xu[(size_t)sq * 32 + lane];
            }
#pragma unroll
            for (int q = 0; q < 8; ++q) {
                a0 = fmaf(wb[q], blo(u[q].x), a0);
                a1 = fmaf(wb[q], bhi(u[q].x), a1);
                a2 = fmaf(wb[q], blo(u[q].y), a2);
                a3 = fmaf(wb[q], bhi(u[q].y), a3);
            }
        }
        for (; t + 4 <= m; t += 4) {
            uint2 u[4]; float wb[4];
#pragma unroll
            for (int q = 0; q < 4; ++q) {
                int sq = __shfl(s, t + q, 32);
                wb[q] = __shfl(wv, t + q, 32);
                u[q] = Xu[(size_t)sq * 32 + lane];
            }
#pragma unroll
            for (int q = 0; q < 4; ++q) {
                a0 = fmaf(wb[q], blo(u[q].x), a0);
                a1 = fmaf(wb[q], bhi(u[q].x), a1);
                a2 = fmaf(wb[q], blo(u[q].y), a2);
                a3 = fmaf(wb[q], bhi(u[q].y), a3);
            }
        }
        for (; t < m; ++t) {
            int ss = __shfl(s, t, 32);
            float ww = __shfl(wv, t, 32);
            uint2 u = Xu[(size_t)ss * 32 + lane];
            a0 = fmaf(ww, blo(u.x), a0); a1 = fmaf(ww, bhi(u.x), a1);
            a2 = fmaf(ww, blo(u.y), a2); a3 = fmaf(ww, bhi(u.y), a3);
        }
    }
    float id = dn * dn;
    uint2 u1n = Xu[(size_t)n * 32 + lane];
    uint2 u0n = ((const uint2*)X0b)[(size_t)n * 32 + lane];
    uint2 ow;
    ow.x = (uint)f2b(-2.f * (a0 + blo(u1n.x) * id) - blo(u0n.x))
         | ((uint)f2b(-2.f * (a1 + bhi(u1n.x) * id) - bhi(u0n.x)) << 16);
    ow.y = (uint)f2b(-2.f * (a2 + blo(u1n.y) * id) - blo(u0n.y))
         | ((uint)f2b(-2.f * (a3 + bhi(u1n.y) * id) - bhi(u0n.y)) << 16);
    ((uint2*)(Rb + (size_t)n * DIM))[lane] = ow;
}

// MFMA GEMM: outb = bf16(relu([X0|X1|X2] @ W + bias)). 128x128 per block,
// 4 waves each 64x64 quadrant as 4x4 16x16x32 bf16 MFMA tiles.
// Aliasing (outb == X0b) safe: block reads only its own 128 rows, writes last.
__global__ __launch_bounds__(256) void k_gemm(
        const ushort* __restrict__ X0b, const ushort* __restrict__ X1b,
        const ushort* __restrict__ X2b, const ushort* __restrict__ Wt,
        const float* __restrict__ bias, ushort* __restrict__ outb) {
    __shared__ ushort As[128 * PADK];
    __shared__ ushort Bs[128 * PADK];
    int tid = threadIdx.x;
    int nbase = blockIdx.x * 128;
    int wave = tid >> 6, lane = tid & 63;
    int wr = wave >> 1, wc = wave & 1;
    int l15 = lane & 15, quad = lane >> 4;

    float4v acc[4][4];
#pragma unroll
    for (int i = 0; i < 4; ++i)
#pragma unroll
        for (int j = 0; j < 4; ++j) acc[i][j] = (float4v)0.f;

    int srow = tid >> 1, shalf = tid & 1;
    int gm = nbase + srow; if (gm >= NN) gm = NN - 1;

    for (int c = 0; c < 12; ++c) {
        int part = c >> 2;
        int k0 = (c & 3) * 32;
        const ushort* Xp = (part == 0) ? X0b : ((part == 1) ? X1b : X2b);
        const uint4* ga = (const uint4*)(Xp + (size_t)gm * DIM + k0 + shalf * 16);
        uint4 a0 = ga[0], a1 = ga[1];
        const uint4* gb = (const uint4*)(Wt + (size_t)srow * KD + c * 32 + shalf * 16);
        uint4 b0 = gb[0], b1 = gb[1];
        __syncthreads();
        uint4* pa = (uint4*)(As + srow * PADK + shalf * 16);
        pa[0] = a0; pa[1] = a1;
        uint4* pb = (uint4*)(Bs + srow * PADK + shalf * 16);
        pb[0] = b0; pb[1] = b1;
        __syncthreads();
        short8 af[4], bf[4];
#pragma unroll
        for (int i = 0; i < 4; ++i) {
            af[i] = *(const short8*)(As + (wr * 64 + i * 16 + l15) * PADK + quad * 8);
            bf[i] = *(const short8*)(Bs + (wc * 64 + i * 16 + l15) * PADK + quad * 8);
        }
#pragma unroll
        for (int i = 0; i < 4; ++i)
#pragma unroll
            for (int j = 0; j < 4; ++j)
                acc[i][j] = __builtin_amdgcn_mfma_f32_16x16x32_bf16(
                    af[i], bf[j], acc[i][j], 0, 0, 0);
    }

    float bv[4];
#pragma unroll
    for (int j = 0; j < 4; ++j) bv[j] = bias[wc * 64 + j * 16 + l15];
#pragma unroll
    for (int i = 0; i < 4; ++i) {
#pragma unroll
        for (int r = 0; r < 4; ++r) {
            int node = nbase + wr * 64 + i * 16 + quad * 4 + r;
            if (node < NN) {
#pragma unroll
                for (int j = 0; j < 4; ++j) {
                    int col = wc * 64 + j * 16 + l15;
                    outb[(size_t)node * DIM + col] =
                        f2b(fmaxf(acc[i][j][r] + bv[j], 0.f));
                }
            }
        }
    }
}

// Last-layer GEMM with fused prediction head.
__global__ __launch_bounds__(256) void k_gemm_pred(
        const ushort* __restrict__ X0b, const ushort* __restrict__ X1b,
        const ushort* __restrict__ X2b, const ushort* __restrict__ Wt,
        const float* __restrict__ bias, const float* __restrict__ pw,
        const float* __restrict__ pb, float* __restrict__ logits) {
    __shared__ ushort As[128 * PADK];
    __shared__ ushort Bs[128 * PADK];
    __shared__ float lsum[128];
    int tid = threadIdx.x;
    int nbase = blockIdx.x * 128;
    int wave = tid >> 6, lane = tid & 63;
    int wr = wave >> 1, wc = wave & 1;
    int l15 = lane & 15, quad = lane >> 4;

    float4v acc[4][4];
#pragma unroll
    for (int i = 0; i < 4; ++i)
#pragma unroll
        for (int j = 0; j < 4; ++j) acc[i][j] = (float4v)0.f;

    int srow = tid >> 1, shalf = tid & 1;
    int gm = nbase + srow; if (gm >= NN) gm = NN - 1;

    for (int c = 0; c < 12; ++c) {
        int part = c >> 2;
        int k0 = (c & 3) * 32;
        const ushort* Xp = (part == 0) ? X0b : ((part == 1) ? X1b : X2b);
        const uint4* ga = (const uint4*)(Xp + (size_t)gm * DIM + k0 + shalf * 16);
        uint4 a0 = ga[0], a1 = ga[1];
        const uint4* gb = (const uint4*)(Wt + (size_t)srow * KD + c * 32 + shalf * 16);
        uint4 b0 = gb[0], b1 = gb[1];
        __syncthreads();
        uint4* pa = (uint4*)(As + srow * PADK + shalf * 16);
        pa[0] = a0; pa[1] = a1;
        uint4* pb2 = (uint4*)(Bs + srow * PADK + shalf * 16);
        pb2[0] = b0; pb2[1] = b1;
        __syncthreads();
        short8 af[4], bf[4];
#pragma unroll
        for (int i = 0; i < 4; ++i) {
            af[i] = *(const short8*)(As + (wr * 64 + i * 16 + l15) * PADK + quad * 8);
            bf[i] = *(const short8*)(Bs + (wc * 64 + i * 16 + l15) * PADK + quad * 8);
        }
#pragma unroll
        for (int i = 0; i < 4; ++i)
#pragma unroll
            for (int j = 0; j < 4; ++j)
                acc[i][j] = __builtin_amdgcn_mfma_f32_16x16x32_bf16(
                    af[i], bf[j], acc[i][j], 0, 0, 0);
    }

    __syncthreads();
    if (tid < 128) lsum[tid] = 0.f;
    __syncthreads();
    float bv[4], pwv[4];
#pragma unroll
    for (int j = 0; j < 4; ++j) {
        int col = wc * 64 + j * 16 + l15;
        bv[j] = bias[col];
        pwv[j] = pw[col];
    }
#pragma unroll
    for (int i = 0; i < 4; ++i) {
#pragma unroll
        for (int r = 0; r < 4; ++r) {
            float local = 0.f;
#pragma unroll
            for (int j = 0; j < 4; ++j)
                local = fmaf(fmaxf(acc[i][j][r] + bv[j], 0.f), pwv[j], local);
            local += __shfl_xor(local, 1, 64);
            local += __shfl_xor(local, 2, 64);
            local += __shfl_xor(local, 4, 64);
            local += __shfl_xor(local, 8, 64);
            if (l15 == 0)
                atomicAdd(&lsum[wr * 64 + i * 16 + quad * 4 + r], local);
        }
    }
    __syncthreads();
    if (tid < 128) {
        int node = nbase + tid;
        if (node < NN) logits[node] = lsum[tid] + pb[0];
    }
}

extern "C" void kernel_launch(void* const* d_in, const int* in_sizes, int n_in,
                              void* d_out, int out_size, void* d_ws, size_t ws_size,
                              hipStream_t stream) {
    int i_weights = 0, i_src = 1, i_dst = 2, i_lw = 3, i_lb = 4,
        i_cw = 5, i_cb = 6, i_pw = 7, i_pb = 8;
    {
        int seen600k = 0, seen128 = 0;
        for (int i = 0; i < n_in; ++i) {
            int s = in_sizes[i];
            if (s == 50000) i_weights = i;
            else if (s == 600000) { if (seen600k == 0) i_src = i; else i_dst = i; ++seen600k; }
            else if (s == 128) { if (seen128 == 0) i_lw = i; else if (seen128 == 1) i_lb = i; else i_pw = i; ++seen128; }
            else if (s == 147456) i_cw = i;
            else if (s == 384) i_cb = i;
            else if (s == 1) i_pb = i;
        }
    }
    const float* weights = (const float*)d_in[i_weights];
    const int*   src     = (const int*)d_in[i_src];
    const int*   dst     = (const int*)d_in[i_dst];
    const float* lin_w   = (const float*)d_in[i_lw];
    const float* lin_b   = (const float*)d_in[i_lb];
    const float* cheb_w  = (const float*)d_in[i_cw];
    const float* cheb_b  = (const float*)d_in[i_cb];
    const float* pred_w  = (const float*)d_in[i_pw];
    const float* pred_b  = (const float*)d_in[i_pb];
    float* out = (float*)d_out;

    // Workspace (~44 MB):
    float*  ws      = (float*)d_ws;
    float*  dinv    = ws;                            // 50048 floats
    int*    offs    = (int*)(ws + 50048);            // 50056 ints
    ushort* csr_u16 = (ushort*)(offs + 50056);       // 600000 ushorts (300032 int-slots)
    int*    cnt     = (int*)csr_u16 + 300032;        // 50176 ints
    int*    incl    = cnt + 50176;                   // 50176 ints
    int*    bsums   = incl + 50176;                  // 256 ints
    ushort* Pb      = (ushort*)(bsums + 256);        // 6.4M bf16 (X0 / state)
    ushort* Qb      = Pb + (size_t)NN * DIM;         // 6.4M bf16 (X1)
    ushort* Rb      = Qb + (size_t)NN * DIM;         // 6.4M bf16 (X2)
    ushort* Wtb     = Rb + (size_t)NN * DIM;         // 442368 bf16

    // --- CSR build + weight transpose (once per launch) ---
    k_init<<<625, 256, 0, stream>>>(cnt, cheb_w, Wtb);
    k_hist<<<2344, 256, 0, stream>>>(dst, cnt);
    k_scan1<<<196, 256, 0, stream>>>(cnt, incl, bsums, dinv);
    k_scan3<<<196, 256, 0, stream>>>(cnt, incl, bsums, offs);
    k_fill<<<2344, 256, 0, stream>>>(src, dst, incl, csr_u16);

    // --- network ---
    // layer 1 (rank-1 gather1, writes Pb too)
    k_gather1_l1<<<12500, 256, 0, stream>>>(weights, lin_w, lin_b, offs, csr_u16,
                                            dinv, Qb, Pb);
    k_gather2<<<6250, 256, 0, stream>>>(Qb, Pb, offs, csr_u16, dinv, Rb);
    k_gemm<<<391, 256, 0, stream>>>(Pb, Qb, Rb, Wtb, cheb_b, Pb);
    // layer 2
    k_gather1<<<6250, 256, 0, stream>>>(Pb, offs, csr_u16, dinv, Qb);
    k_gather2<<<6250, 256, 0, stream>>>(Qb, Pb, offs, csr_u16, dinv, Rb);
    k_gemm<<<391, 256, 0, stream>>>(Pb, Qb, Rb, Wtb + (size_t)KD * DIM,
                                    cheb_b + DIM, Pb);
    // layer 3 (fused prediction head)
    k_gather1<<<6250, 256, 0, stream>>>(Pb, offs, csr_u16, dinv, Qb);
    k_gather2<<<6250, 256, 0, stream>>>(Qb, Pb, offs, csr_u16, dinv, Rb);
    k_gemm_pred<<<391, 256, 0, stream>>>(Pb, Qb, Rb, Wtb + (size_t)2 * KD * DIM,
                                         cheb_b + 2 * DIM, pred_w, pred_b, out);
}